// Round 7
// baseline (871.415 us; speedup 1.0000x reference)
//
#include <hip/hip_runtime.h>

#define N_NODES 100000
#define N_EDGES 100000
#define NNZ_C   600000
#define CAP     16          // bucket = one 64-B line; overflow list handles tail
#define OVF_MAX 4096

typedef unsigned short u16;
typedef __attribute__((ext_vector_type(8))) short short8;
typedef __attribute__((ext_vector_type(4))) float float4v;

__device__ __forceinline__ void atomAddF(float* p, float v) {
    unsafeAtomicAdd(p, v);
}

__device__ __forceinline__ u16 f2bf(float f) {     // RNE fp32 -> bf16
    union { float f; unsigned int i; } x; x.f = f;
    unsigned int r = x.i + 0x7FFFu + ((x.i >> 16) & 1u);
    return (u16)(r >> 16);
}
__device__ __forceinline__ float bf2f(u16 u) {
    union { float f; unsigned int i; } x; x.i = ((unsigned int)u) << 16; return x.f;
}

__device__ __forceinline__ short8 cvt_frag(float4 a, float4 b) {
    union { short8 s; u16 u[8]; } o;
    o.u[0] = f2bf(a.x); o.u[1] = f2bf(a.y); o.u[2] = f2bf(a.z); o.u[3] = f2bf(a.w);
    o.u[4] = f2bf(b.x); o.u[5] = f2bf(b.y); o.u[6] = f2bf(b.z); o.u[7] = f2bf(b.w);
    return o.s;
}

// relu(z*A + C) per element; A/C indexed by the fragment's k offset
__device__ __forceinline__ short8 bn_frag(short8 raw, float4 A0, float4 A1,
                                          float4 C0, float4 C1) {
    union { short8 s; u16 u[8]; } in; in.s = raw;
    union { short8 s; u16 u[8]; } o;
    o.u[0] = f2bf(fmaxf(bf2f(in.u[0]) * A0.x + C0.x, 0.0f));
    o.u[1] = f2bf(fmaxf(bf2f(in.u[1]) * A0.y + C0.y, 0.0f));
    o.u[2] = f2bf(fmaxf(bf2f(in.u[2]) * A0.z + C0.z, 0.0f));
    o.u[3] = f2bf(fmaxf(bf2f(in.u[3]) * A0.w + C0.w, 0.0f));
    o.u[4] = f2bf(fmaxf(bf2f(in.u[4]) * A1.x + C1.x, 0.0f));
    o.u[5] = f2bf(fmaxf(bf2f(in.u[5]) * A1.y + C1.y, 0.0f));
    o.u[6] = f2bf(fmaxf(bf2f(in.u[6]) * A1.z + C1.z, 0.0f));
    o.u[7] = f2bf(fmaxf(bf2f(in.u[7]) * A1.w + C1.w, 0.0f));
    return o.s;
}

// ---------------- degree-count + bucket fill --------------------------------
// Data stores use atomicExch: device atomics execute near-memory and write
// back at ~8-B granularity (R1 evidence: 7.8 B/atomic), avoiding the 64-B
// line writeback per scattered plain store (74 MB -> ~12 MB).
__global__ __launch_bounds__(256) void fill_direct(
    const int* __restrict__ nidx, const int* __restrict__ eidx,
    int* __restrict__ cb, int* __restrict__ cd,
    int* __restrict__ colB, int* __restrict__ colD,
    uint2* __restrict__ ovfB, uint2* __restrict__ ovfD,
    int* __restrict__ ovfCntB, int* __restrict__ ovfCntD, int nnz)
{
    int i = blockIdx.x * 256 + threadIdx.x;
    if (i < nnz) {
        int n = nidx[i], e = eidx[i];
        int pb = atomicAdd(&cb[e], 1);
        if (pb < CAP) atomicExch(&colB[(e << 4) + pb], n);
        else { int o = atomicAdd(ovfCntB, 1); if (o < OVF_MAX) ovfB[o] = make_uint2((unsigned)e, (unsigned)n); }
        int pd = atomicAdd(&cd[n], 1);
        if (pd < CAP) atomicExch(&colD[(n << 4) + pd], e);
        else { int o = atomicAdd(ovfCntD, 1); if (o < OVF_MAX) ovfD[o] = make_uint2((unsigned)n, (unsigned)e); }
    }
}

// ---------------- fp32 -> bf16 conversion (weights only) --------------------
__global__ __launch_bounds__(256) void convert_w(
    const float* __restrict__ W1, const float* __restrict__ W2,
    const float* __restrict__ W3, u16* __restrict__ W1b,
    u16* __restrict__ W2b, u16* __restrict__ W3b)
{
    int i = blockIdx.x * 256 + threadIdx.x;
    const float* src; u16* dst; int base;
    if      (i <  8192) { src = W1; dst = W1b; base = i; }
    else if (i < 12288) { src = W2; dst = W2b; base = i - 8192; }
    else if (i < 16384) { src = W3; dst = W3b; base = i - 12288; }
    else return;
    float4 v = *(const float4*)(src + (size_t)base * 4);
    ushort4 o;
    o.x = f2bf(v.x); o.y = f2bf(v.y); o.z = f2bf(v.z); o.w = f2bf(v.w);
    *(ushort4*)(dst + (size_t)base * 4) = o;
}

// ---------------- bf16 MFMA GEMM with fused A-path preprocessing ------------
// AMODE 1: A is fp32, convert in-register (GEMM0).
// AMODE 2: A is bf16 pre-BN z; apply relu(z*As+Cs), As/Cs from raw moments.
template<int KDIM, int AMODE>
__global__ __launch_bounds__(256) void gemm_mfma(
    const void* __restrict__ Aptr, const u16* __restrict__ Wb,
    u16* __restrict__ C, int M,
    const float* __restrict__ gsum, const float* __restrict__ gsq,
    const float* __restrict__ gam, const float* __restrict__ bet, float invM)
{
    __shared__ __attribute__((aligned(16))) u16 Wt[128 * 128];   // 32 KB
    __shared__ __attribute__((aligned(16))) u16 tb[4][16][136];  // 17 KB
    __shared__ __attribute__((aligned(16))) float As[128];
    __shared__ __attribute__((aligned(16))) float Cs[128];
    const int tid = threadIdx.x;
    if (AMODE == 2 && tid < 128) {
        float s1 = gsum[tid] * invM;
        float var = gsq[tid] * invM - s1 * s1;
        if (var < 0.0f) var = 0.0f;
        float sc = gam[tid] * rsqrtf(var + 1e-5f);
        As[tid] = sc;
        Cs[tid] = bet[tid] - s1 * sc;   // conv bias cancels under BN
    }
    const int wave = tid >> 6, lane = tid & 63;
    const int l16 = lane & 15, quad = lane >> 4;
    const int rowt = blockIdx.x * 128 + wave * 32;
    const int r0 = rowt + l16, r1 = rowt + 16 + l16;
    const bool v0 = r0 < M, v1 = r1 < M;
    const u16*   Ab = (const u16*)Aptr;
    const float* Af = (const float*)Aptr;
    const size_t rb0 = (size_t)(v0 ? r0 : 0) * KDIM + quad * 8;
    const size_t rb1 = (size_t)(v1 ? r1 : 0) * KDIM + quad * 8;

    float4v acc[2][8];
#pragma unroll
    for (int g = 0; g < 2; g++)
#pragma unroll
        for (int c = 0; c < 8; c++) acc[g][c] = (float4v)0.0f;

    for (int kc = 0; kc < KDIM; kc += 128) {
        if (kc) __syncthreads();
        for (int i = tid * 4; i < 128 * 128; i += 1024) {
            int k = i >> 7, n0 = i & 127;
            uint2 v = *(const uint2*)(Wb + (size_t)(kc + k) * 128 + n0);
            int kb = k >> 3, kin = k & 7;
            Wt[(n0 + 0) * 128 + (((kb + n0 + 0) & 15) << 3) + kin] = (u16)(v.x & 0xFFFF);
            Wt[(n0 + 1) * 128 + (((kb + n0 + 1) & 15) << 3) + kin] = (u16)(v.x >> 16);
            Wt[(n0 + 2) * 128 + (((kb + n0 + 2) & 15) << 3) + kin] = (u16)(v.y & 0xFFFF);
            Wt[(n0 + 3) * 128 + (((kb + n0 + 3) & 15) << 3) + kin] = (u16)(v.y >> 16);
        }
        __syncthreads();
        for (int k0 = 0; k0 < 128; k0 += 32) {
            short8 af0, af1;
            if (AMODE == 1) {
                af0 = cvt_frag(*(const float4*)(Af + rb0 + kc + k0),
                               *(const float4*)(Af + rb0 + kc + k0 + 4));
                af1 = cvt_frag(*(const float4*)(Af + rb1 + kc + k0),
                               *(const float4*)(Af + rb1 + kc + k0 + 4));
            } else {
                int kb4 = k0 + quad * 8;
                float4 A0 = *(const float4*)&As[kb4], A1 = *(const float4*)&As[kb4 + 4];
                float4 C0 = *(const float4*)&Cs[kb4], C1 = *(const float4*)&Cs[kb4 + 4];
                af0 = bn_frag(*(const short8*)(Ab + rb0 + k0), A0, A1, C0, C1);
                af1 = bn_frag(*(const short8*)(Ab + rb1 + k0), A0, A1, C0, C1);
            }
            if (!v0) af0 = (short8)(short)0;
            if (!v1) af1 = (short8)(short)0;
            const int kb = (k0 >> 3) + quad;
#pragma unroll
            for (int c = 0; c < 8; c++) {
                const int n = c * 16 + l16;
                short8 bf = *(const short8*)&Wt[n * 128 + (((kb + n) & 15) << 3)];
                acc[0][c] = __builtin_amdgcn_mfma_f32_16x16x32_bf16(af0, bf, acc[0][c], 0, 0, 0);
                acc[1][c] = __builtin_amdgcn_mfma_f32_16x16x32_bf16(af1, bf, acc[1][c], 0, 0, 0);
            }
        }
    }
#pragma unroll
    for (int g = 0; g < 2; g++) {
#pragma unroll
        for (int c = 0; c < 8; c++)
#pragma unroll
            for (int r = 0; r < 4; r++)
                tb[wave][quad * 4 + r][c * 16 + l16] = f2bf(acc[g][c][r]);
        asm volatile("s_waitcnt lgkmcnt(0)" ::: "memory");
#pragma unroll
        for (int j = 0; j < 4; j++) {
            int row_l = j * 4 + (lane >> 4);
            int row = rowt + g * 16 + row_l;
            if (row < M) {
                short8 vv = *(const short8*)&tb[wave][row_l][(lane & 15) * 8];
                *(short8*)(C + (size_t)row * 128 + (lane & 15) * 8) = vv;
            }
        }
        if (g == 0) asm volatile("s_waitcnt lgkmcnt(0)" ::: "memory");
    }
}

// ---------------- half-wave gather: dst[r] = (1/cnt[r]) * sum src[members] --
// One destination row per 32-lane half (uint2 = 4 bf16 per lane): 2 rows per
// wave doubles loads in flight. STATS: accumulate per-column raw moments of
// dst into gsum[128]||gsq[128] (per-lane fixed columns -> registers -> one
// 256-atomic flush per block).
template<int STATS>
__global__ __launch_bounds__(256) void gather_half(
    const u16* __restrict__ src, const int* __restrict__ cnt,
    const int* __restrict__ col, u16* __restrict__ dst,
    float* __restrict__ stat, float* __restrict__ zp,
    const uint2* __restrict__ ovf, const int* __restrict__ ovfCnt, int nrows)
{
    if (zp && blockIdx.x == 0) zp[threadIdx.x] = 0.0f;
    const int tid = threadIdx.x;
    const int lane = tid & 63;
    const int l = lane & 31;          // position in half-wave
    const int halfid = tid >> 5;      // 0..7 within block
    const int bsel = lane & 32;       // shfl source base for this half
    const int c4 = l * 4;             // this lane's 4 columns
    float s1a = 0, s1b = 0, s1c = 0, s1d = 0;
    float s2a = 0, s2b = 0, s2c = 0, s2d = 0;

    for (int rr = blockIdx.x * 8; rr < nrows; rr += gridDim.x * 8) {
        int r = rr + halfid;
        if (r < nrows) {
            int c = cnt[r];
            int cc = (c > CAP) ? CAP : c;
            int m = (l < cc) ? col[(r << 4) + l] : 0;
            float a0 = 0, a1 = 0, a2 = 0, a3 = 0;
            int j = 0;
            for (; j + 4 <= cc; j += 4) {
                int s0 = __shfl(m, bsel | j);
                int s1_ = __shfl(m, bsel | (j + 1));
                int s2_ = __shfl(m, bsel | (j + 2));
                int s3_ = __shfl(m, bsel | (j + 3));
                uint2 va = *(const uint2*)&src[(size_t)s0 * 128 + c4];
                uint2 vb = *(const uint2*)&src[(size_t)s1_ * 128 + c4];
                uint2 vc = *(const uint2*)&src[(size_t)s2_ * 128 + c4];
                uint2 vd = *(const uint2*)&src[(size_t)s3_ * 128 + c4];
                a0 += bf2f((u16)(va.x & 0xFFFF)) + bf2f((u16)(vb.x & 0xFFFF))
                    + bf2f((u16)(vc.x & 0xFFFF)) + bf2f((u16)(vd.x & 0xFFFF));
                a1 += bf2f((u16)(va.x >> 16)) + bf2f((u16)(vb.x >> 16))
                    + bf2f((u16)(vc.x >> 16)) + bf2f((u16)(vd.x >> 16));
                a2 += bf2f((u16)(va.y & 0xFFFF)) + bf2f((u16)(vb.y & 0xFFFF))
                    + bf2f((u16)(vc.y & 0xFFFF)) + bf2f((u16)(vd.y & 0xFFFF));
                a3 += bf2f((u16)(va.y >> 16)) + bf2f((u16)(vb.y >> 16))
                    + bf2f((u16)(vc.y >> 16)) + bf2f((u16)(vd.y >> 16));
            }
            for (; j < cc; j++) {
                int s0 = __shfl(m, bsel | j);
                uint2 va = *(const uint2*)&src[(size_t)s0 * 128 + c4];
                a0 += bf2f((u16)(va.x & 0xFFFF));
                a1 += bf2f((u16)(va.x >> 16));
                a2 += bf2f((u16)(va.y & 0xFFFF));
                a3 += bf2f((u16)(va.y >> 16));
            }
            if (c > CAP) {                     // rare: scan overflow list
                int nov = *ovfCnt; if (nov > OVF_MAX) nov = OVF_MAX;
                for (int i2 = 0; i2 < nov; i2++) {
                    uint2 p = ovf[i2];
                    if ((int)p.x == r) {
                        uint2 va = *(const uint2*)&src[(size_t)p.y * 128 + c4];
                        a0 += bf2f((u16)(va.x & 0xFFFF));
                        a1 += bf2f((u16)(va.x >> 16));
                        a2 += bf2f((u16)(va.y & 0xFFFF));
                        a3 += bf2f((u16)(va.y >> 16));
                    }
                }
            }
            float w = (c > 0) ? 1.0f / (float)c : 0.0f;
            a0 *= w; a1 *= w; a2 *= w; a3 *= w;
            uint2 o;
            o.x = (unsigned)f2bf(a0) | ((unsigned)f2bf(a1) << 16);
            o.y = (unsigned)f2bf(a2) | ((unsigned)f2bf(a3) << 16);
            *(uint2*)&dst[(size_t)r * 128 + c4] = o;
            if (STATS) {
                s1a += a0; s2a += a0 * a0;
                s1b += a1; s2b += a1 * a1;
                s1c += a2; s2c += a2 * a2;
                s1d += a3; s2d += a3 * a3;
            }
        }
    }
    if (STATS) {
        __shared__ float red[8][32][8];   // 8 KB
        float* p = red[halfid][l];
        p[0] = s1a; p[1] = s1b; p[2] = s1c; p[3] = s1d;
        p[4] = s2a; p[5] = s2b; p[6] = s2c; p[7] = s2d;
        __syncthreads();
        if (tid < 32) {
            float t0 = 0, t1 = 0, t2 = 0, t3 = 0, q0 = 0, q1 = 0, q2 = 0, q3 = 0;
#pragma unroll
            for (int h = 0; h < 8; h++) {
                const float* s = red[h][tid];
                t0 += s[0]; t1 += s[1]; t2 += s[2]; t3 += s[3];
                q0 += s[4]; q1 += s[5]; q2 += s[6]; q3 += s[7];
            }
            int cb4 = tid * 4;
            atomAddF(&stat[cb4 + 0], t0); atomAddF(&stat[cb4 + 1], t1);
            atomAddF(&stat[cb4 + 2], t2); atomAddF(&stat[cb4 + 3], t3);
            atomAddF(&stat[128 + cb4 + 0], q0); atomAddF(&stat[128 + cb4 + 1], q1);
            atomAddF(&stat[128 + cb4 + 2], q2); atomAddF(&stat[128 + cb4 + 3], q3);
        }
    }
}

// ---------------- MFMA classifier with fused BN on the A-path ---------------
__global__ __launch_bounds__(256) void classifier_mfma(
    const u16* __restrict__ Z, const float* __restrict__ Wc1,
    const float* __restrict__ bc1, const float* __restrict__ Wc2,
    const float* __restrict__ bc2, float* __restrict__ out, int M,
    const float* __restrict__ gsum, const float* __restrict__ gsq,
    const float* __restrict__ gam, const float* __restrict__ bet, float invM)
{
    __shared__ __attribute__((aligned(16))) u16 W1t[64 * 128];   // 16 KB
    __shared__ __attribute__((aligned(16))) u16 W2t[16 * 64];    // 2 KB
    __shared__ __attribute__((aligned(16))) u16 hs[128][72];     // 18.4 KB
    __shared__ __attribute__((aligned(16))) float As[128];
    __shared__ __attribute__((aligned(16))) float Cs[128];
    const int tid = threadIdx.x;
    if (tid < 128) {
        float s1 = gsum[tid] * invM;
        float var = gsq[tid] * invM - s1 * s1;
        if (var < 0.0f) var = 0.0f;
        float sc = gam[tid] * rsqrtf(var + 1e-5f);
        As[tid] = sc;
        Cs[tid] = bet[tid] - s1 * sc;
    }
    for (int i = tid; i < 64 * 128; i += 256) {   // i = k*64 + n
        int k = i >> 6, n = i & 63;
        int kb = k >> 3, kin = k & 7;
        W1t[n * 128 + (((kb + n) & 15) << 3) + kin] = f2bf(Wc1[i]);
    }
    for (int i = tid; i < 16 * 64; i += 256) {    // i = k*16 + n
        int k = i >> 4, n = i & 15;
        W2t[n * 64 + k] = (n < 10) ? f2bf(Wc2[k * 10 + n]) : (u16)0;
    }
    __syncthreads();

    const int wave = tid >> 6, lane = tid & 63;
    const int l16 = lane & 15, quad = lane >> 4;
    const int rowt = blockIdx.x * 128 + wave * 32;
    const int r0 = rowt + l16, r1 = rowt + 16 + l16;
    const bool v0 = r0 < M, v1 = r1 < M;
    const u16* a0p = Z + (size_t)(v0 ? r0 : 0) * 128 + quad * 8;
    const u16* a1p = Z + (size_t)(v1 ? r1 : 0) * 128 + quad * 8;

    float4v acc[2][4];
#pragma unroll
    for (int g = 0; g < 2; g++)
#pragma unroll
        for (int c = 0; c < 4; c++) acc[g][c] = (float4v)0.0f;

#pragma unroll
    for (int k0 = 0; k0 < 128; k0 += 32) {
        int kb4 = k0 + quad * 8;
        float4 A0 = *(const float4*)&As[kb4], A1 = *(const float4*)&As[kb4 + 4];
        float4 C0 = *(const float4*)&Cs[kb4], C1 = *(const float4*)&Cs[kb4 + 4];
        short8 af0 = bn_frag(*(const short8*)(a0p + k0), A0, A1, C0, C1);
        short8 af1 = bn_frag(*(const short8*)(a1p + k0), A0, A1, C0, C1);
        if (!v0) af0 = (short8)(short)0;
        if (!v1) af1 = (short8)(short)0;
        const int kb = (k0 >> 3) + quad;
#pragma unroll
        for (int c = 0; c < 4; c++) {
            const int n = c * 16 + l16;
            short8 bf = *(const short8*)&W1t[n * 128 + (((kb + n) & 15) << 3)];
            acc[0][c] = __builtin_amdgcn_mfma_f32_16x16x32_bf16(af0, bf, acc[0][c], 0, 0, 0);
            acc[1][c] = __builtin_amdgcn_mfma_f32_16x16x32_bf16(af1, bf, acc[1][c], 0, 0, 0);
        }
    }
#pragma unroll
    for (int g = 0; g < 2; g++)
#pragma unroll
        for (int c = 0; c < 4; c++) {
            float b = bc1[c * 16 + l16];
#pragma unroll
            for (int r = 0; r < 4; r++)
                hs[wave * 32 + g * 16 + quad * 4 + r][c * 16 + l16] =
                    f2bf(fmaxf(acc[g][c][r] + b, 0.0f));
        }
    asm volatile("s_waitcnt lgkmcnt(0)" ::: "memory");

    float4v a2[2];
    a2[0] = (float4v)0.0f; a2[1] = (float4v)0.0f;
#pragma unroll
    for (int k0 = 0; k0 < 64; k0 += 32) {
        short8 bf = *(const short8*)&W2t[l16 * 64 + k0 + quad * 8];
#pragma unroll
        for (int g = 0; g < 2; g++) {
            short8 af = *(const short8*)&hs[wave * 32 + g * 16 + l16][k0 + quad * 8];
            a2[g] = __builtin_amdgcn_mfma_f32_16x16x32_bf16(af, bf, a2[g], 0, 0, 0);
        }
    }
    if (l16 < 10) {
        float b2 = bc2[l16];
#pragma unroll
        for (int g = 0; g < 2; g++)
#pragma unroll
            for (int r = 0; r < 4; r++) {
                int row = rowt + g * 16 + quad * 4 + r;
                if (row < M) out[(size_t)row * 10 + l16] = a2[g][r] + b2;
            }
    }
}

// ---------------- launch ----------------------------------------------------
extern "C" void kernel_launch(void* const* d_in, const int* in_sizes, int n_in,
                              void* d_out, int out_size, void* d_ws, size_t ws_size,
                              hipStream_t stream)
{
    const int M   = N_NODES;
    const int NE  = N_EDGES;
    const int nnz = NNZ_C;

    const float* x   = (const float*)d_in[0];
    const int*  nidx = (const int*)d_in[1];
    const int*  eidx = nidx + nnz;
    const float* W1  = (const float*)d_in[2];
    const float* W2  = (const float*)d_in[4];
    const float* W3  = (const float*)d_in[6];
    const float* g1  = (const float*)d_in[8];
    const float* bt1 = (const float*)d_in[9];
    const float* g2  = (const float*)d_in[10];
    const float* bt2 = (const float*)d_in[11];
    const float* g3  = (const float*)d_in[12];
    const float* bt3 = (const float*)d_in[13];
    const float* Wc1 = (const float*)d_in[14];
    const float* bc1 = (const float*)d_in[15];
    const float* Wc2 = (const float*)d_in[16];
    const float* bc2 = (const float*)d_in[17];
    float* out = (float*)d_out;

    // ---- workspace carve-up ----
    const size_t SZH = (size_t)M * 128 * sizeof(u16);   // 25.6 MB
    char* ws = (char*)d_ws;
    u16* Y = (u16*)(ws);                     // GEMM output (bf16)
    u16* E = (u16*)(ws + SZH);               // edge features (bf16)
    u16* Z = (u16*)(ws + 2 * SZH);           // node agg, pre-BN (bf16)
    int* ib = (int*)(ws + 3 * SZH);
    int*   cb      = ib;                     // edge sizes / cursors [100000]
    int*   cd      = ib + 100000;            // node degrees / cursors
    int*   ovfCntB = ib + 200000;
    int*   ovfCntD = ib + 200001;
    int*   colB    = ib + 200016;            // 64-B aligned; [100000*16]
    int*   colD    = ib + 200016 + NE * CAP;
    uint2* ovfB    = (uint2*)(ib + 200016 + (NE + M) * CAP);
    uint2* ovfD    = ovfB + OVF_MAX;
    float* fb = (float*)(ovfD + OVF_MAX);
    float* gsum = fb;                        // [128]; gsq contiguous after
    u16* wbuf = (u16*)(fb + 256);
    u16* W1b = wbuf;                         // 256*128 bf16
    u16* W2b = wbuf + 32768;                 // 128*128
    u16* W3b = wbuf + 49152;                 // 128*128

    const int ntiles = (M + 127) / 128;
    const float invM = 1.0f / (float)M;

    // ---- index preprocessing ----
    hipMemsetAsync(cb, 0, 800008, stream);   // cb + cd + both overflow counters
    fill_direct<<<(nnz + 255) / 256, 256, 0, stream>>>(
        nidx, eidx, cb, cd, colB, colD, ovfB, ovfD, ovfCntB, ovfCntD, nnz);
    convert_w<<<64, 256, 0, stream>>>(W1, W2, W3, W1b, W2b, W3b);

    const float* gin[3]  = { g1, g2, g3 };
    const float* btin[3] = { bt1, bt2, bt3 };
    const u16*   Wbf[3]  = { W1b, W2b, W3b };

    for (int L = 0; L < 3; L++) {
        if (L == 0)
            gemm_mfma<256, 1><<<ntiles, 256, 0, stream>>>(
                x, Wbf[0], Y, M, nullptr, nullptr, nullptr, nullptr, 0.0f);
        else
            gemm_mfma<128, 2><<<ntiles, 256, 0, stream>>>(
                Z, Wbf[L], Y, M, gsum, gsum + 128, gin[L - 1], btin[L - 1], invM);
        // edge aggregation; block 0 zeros gsum||gsq for the node pass
        gather_half<0><<<(NE + 7) / 8, 256, 0, stream>>>(
            Y, cb, colB, E, nullptr, gsum, ovfB, ovfCntB, NE);
        // node aggregation with fused raw-moment stats
        gather_half<1><<<1024, 256, 0, stream>>>(
            E, cd, colD, Z, gsum, nullptr, ovfD, ovfCntD, M);
    }

    classifier_mfma<<<ntiles, 256, 0, stream>>>(
        Z, Wc1, bc1, Wc2, bc2, out, M, gsum, gsum + 128, gin[2], btin[2], invM);
}

// Round 8
// 653.716 us; speedup vs baseline: 1.3330x; 1.3330x over previous
//
#include <hip/hip_runtime.h>

#define N_NODES 100000
#define N_EDGES 100000
#define NNZ_C   600000
#define CAP     16          // bucket = one 64-B line; overflow list handles tail
#define OVF_MAX 4096

typedef unsigned short u16;
typedef __attribute__((ext_vector_type(8))) short short8;
typedef __attribute__((ext_vector_type(4))) float float4v;

__device__ __forceinline__ void atomAddF(float* p, float v) {
    unsafeAtomicAdd(p, v);
}

__device__ __forceinline__ u16 f2bf(float f) {     // RNE fp32 -> bf16
    union { float f; unsigned int i; } x; x.f = f;
    unsigned int r = x.i + 0x7FFFu + ((x.i >> 16) & 1u);
    return (u16)(r >> 16);
}
__device__ __forceinline__ float bf2f(u16 u) {
    union { float f; unsigned int i; } x; x.i = ((unsigned int)u) << 16; return x.f;
}

__device__ __forceinline__ short8 cvt_frag(float4 a, float4 b) {
    union { short8 s; u16 u[8]; } o;
    o.u[0] = f2bf(a.x); o.u[1] = f2bf(a.y); o.u[2] = f2bf(a.z); o.u[3] = f2bf(a.w);
    o.u[4] = f2bf(b.x); o.u[5] = f2bf(b.y); o.u[6] = f2bf(b.z); o.u[7] = f2bf(b.w);
    return o.s;
}

// relu(z*A + C) per element; A/C indexed by the fragment's k offset
__device__ __forceinline__ short8 bn_frag(short8 raw, float4 A0, float4 A1,
                                          float4 C0, float4 C1) {
    union { short8 s; u16 u[8]; } in; in.s = raw;
    union { short8 s; u16 u[8]; } o;
    o.u[0] = f2bf(fmaxf(bf2f(in.u[0]) * A0.x + C0.x, 0.0f));
    o.u[1] = f2bf(fmaxf(bf2f(in.u[1]) * A0.y + C0.y, 0.0f));
    o.u[2] = f2bf(fmaxf(bf2f(in.u[2]) * A0.z + C0.z, 0.0f));
    o.u[3] = f2bf(fmaxf(bf2f(in.u[3]) * A0.w + C0.w, 0.0f));
    o.u[4] = f2bf(fmaxf(bf2f(in.u[4]) * A1.x + C1.x, 0.0f));
    o.u[5] = f2bf(fmaxf(bf2f(in.u[5]) * A1.y + C1.y, 0.0f));
    o.u[6] = f2bf(fmaxf(bf2f(in.u[6]) * A1.z + C1.z, 0.0f));
    o.u[7] = f2bf(fmaxf(bf2f(in.u[7]) * A1.w + C1.w, 0.0f));
    return o.s;
}

// ---------------- degree-count + bucket fill (atomicExch data stores) -------
__global__ __launch_bounds__(256) void fill_direct(
    const int* __restrict__ nidx, const int* __restrict__ eidx,
    int* __restrict__ cb, int* __restrict__ cd,
    int* __restrict__ colB, int* __restrict__ colD,
    uint2* __restrict__ ovfB, uint2* __restrict__ ovfD,
    int* __restrict__ ovfCntB, int* __restrict__ ovfCntD, int nnz)
{
    int i = blockIdx.x * 256 + threadIdx.x;
    if (i < nnz) {
        int n = nidx[i], e = eidx[i];
        int pb = atomicAdd(&cb[e], 1);
        if (pb < CAP) atomicExch(&colB[(e << 4) + pb], n);
        else { int o = atomicAdd(ovfCntB, 1); if (o < OVF_MAX) ovfB[o] = make_uint2((unsigned)e, (unsigned)n); }
        int pd = atomicAdd(&cd[n], 1);
        if (pd < CAP) atomicExch(&colD[(n << 4) + pd], e);
        else { int o = atomicAdd(ovfCntD, 1); if (o < OVF_MAX) ovfD[o] = make_uint2((unsigned)n, (unsigned)e); }
    }
}

// ---------------- weights: fp32 -> bf16, pre-swizzled to the LDS image ------
// Image per 128-k chunk: img[n*128 + rot(k,n)] with rot = ((k/8 + n)&15)*8 + k%8.
// GEMM staging then becomes a straight 32 KB copy (no bit-twiddling per block).
__global__ __launch_bounds__(256) void convert_w(
    const float* __restrict__ W1, const float* __restrict__ W2,
    const float* __restrict__ W3, u16* __restrict__ W1b,
    u16* __restrict__ W2b, u16* __restrict__ W3b)
{
    int i = blockIdx.x * 256 + threadIdx.x;   // 65536 total
    const float* src; u16* dst; int idx;
    if      (i < 32768) { src = W1; dst = W1b; idx = i; }
    else if (i < 49152) { src = W2; dst = W2b; idx = i - 32768; }
    else                { src = W3; dst = W3b; idx = i - 49152; }
    int k = idx >> 7, n = idx & 127;
    int chunk = k >> 7, kl = k & 127;
    int kb = kl >> 3, kin = kl & 7;
    dst[chunk * 16384 + n * 128 + (((kb + n) & 15) << 3) + kin] = f2bf(src[idx]);
}

// ---------------- bf16 MFMA GEMM with fused A-path preprocessing ------------
// AMODE 1: A is fp32, convert in-register (GEMM0).
// AMODE 2: A is bf16 pre-BN z; apply relu(z*As+Cs), As/Cs from raw moments.
// Wb points at the pre-swizzled image; staging is a plain uint4 copy.
template<int KDIM, int AMODE>
__global__ __launch_bounds__(256) void gemm_mfma(
    const void* __restrict__ Aptr, const u16* __restrict__ Wb,
    u16* __restrict__ C, int M,
    const float* __restrict__ gsum, const float* __restrict__ gsq,
    const float* __restrict__ gam, const float* __restrict__ bet, float invM)
{
    __shared__ __attribute__((aligned(16))) u16 Wt[128 * 128];   // 32 KB
    __shared__ __attribute__((aligned(16))) u16 tb[4][16][136];  // 17 KB
    __shared__ __attribute__((aligned(16))) float As[128];
    __shared__ __attribute__((aligned(16))) float Cs[128];
    const int tid = threadIdx.x;
    if (AMODE == 2 && tid < 128) {
        float s1 = gsum[tid] * invM;
        float var = gsq[tid] * invM - s1 * s1;
        if (var < 0.0f) var = 0.0f;
        float sc = gam[tid] * rsqrtf(var + 1e-5f);
        As[tid] = sc;
        Cs[tid] = bet[tid] - s1 * sc;   // conv bias cancels under BN
    }
    const int wave = tid >> 6, lane = tid & 63;
    const int l16 = lane & 15, quad = lane >> 4;
    const int rowt = blockIdx.x * 128 + wave * 32;
    const int r0 = rowt + l16, r1 = rowt + 16 + l16;
    const bool v0 = r0 < M, v1 = r1 < M;
    const u16*   Ab = (const u16*)Aptr;
    const float* Af = (const float*)Aptr;
    const size_t rb0 = (size_t)(v0 ? r0 : 0) * KDIM + quad * 8;
    const size_t rb1 = (size_t)(v1 ? r1 : 0) * KDIM + quad * 8;

    float4v acc[2][8];
#pragma unroll
    for (int g = 0; g < 2; g++)
#pragma unroll
        for (int c = 0; c < 8; c++) acc[g][c] = (float4v)0.0f;

    for (int kc = 0; kc < KDIM; kc += 128) {
        if (kc) __syncthreads();
        {
            const uint4* Wsrc = (const uint4*)Wb + (kc >> 7) * 2048;
            uint4* Wdst = (uint4*)Wt;
            for (int i = tid; i < 2048; i += 256) Wdst[i] = Wsrc[i];
        }
        __syncthreads();
        for (int k0 = 0; k0 < 128; k0 += 32) {
            short8 af0, af1;
            if (AMODE == 1) {
                af0 = cvt_frag(*(const float4*)(Af + rb0 + kc + k0),
                               *(const float4*)(Af + rb0 + kc + k0 + 4));
                af1 = cvt_frag(*(const float4*)(Af + rb1 + kc + k0),
                               *(const float4*)(Af + rb1 + kc + k0 + 4));
            } else {
                int kb4 = k0 + quad * 8;
                float4 A0 = *(const float4*)&As[kb4], A1 = *(const float4*)&As[kb4 + 4];
                float4 C0 = *(const float4*)&Cs[kb4], C1 = *(const float4*)&Cs[kb4 + 4];
                af0 = bn_frag(*(const short8*)(Ab + rb0 + k0), A0, A1, C0, C1);
                af1 = bn_frag(*(const short8*)(Ab + rb1 + k0), A0, A1, C0, C1);
            }
            if (!v0) af0 = (short8)(short)0;
            if (!v1) af1 = (short8)(short)0;
            const int kb = (k0 >> 3) + quad;
#pragma unroll
            for (int c = 0; c < 8; c++) {
                const int n = c * 16 + l16;
                short8 bf = *(const short8*)&Wt[n * 128 + (((kb + n) & 15) << 3)];
                acc[0][c] = __builtin_amdgcn_mfma_f32_16x16x32_bf16(af0, bf, acc[0][c], 0, 0, 0);
                acc[1][c] = __builtin_amdgcn_mfma_f32_16x16x32_bf16(af1, bf, acc[1][c], 0, 0, 0);
            }
        }
    }
#pragma unroll
    for (int g = 0; g < 2; g++) {
#pragma unroll
        for (int c = 0; c < 8; c++)
#pragma unroll
            for (int r = 0; r < 4; r++)
                tb[wave][quad * 4 + r][c * 16 + l16] = f2bf(acc[g][c][r]);
        asm volatile("s_waitcnt lgkmcnt(0)" ::: "memory");
#pragma unroll
        for (int j = 0; j < 4; j++) {
            int row_l = j * 4 + (lane >> 4);
            int row = rowt + g * 16 + row_l;
            if (row < M) {
                short8 vv = *(const short8*)&tb[wave][row_l][(lane & 15) * 8];
                *(short8*)(C + (size_t)row * 128 + (lane & 15) * 8) = vv;
            }
        }
        if (g == 0) asm volatile("s_waitcnt lgkmcnt(0)" ::: "memory");
    }
}

// ---------------- quarter-wave gather: 16 lanes/row, uint4 (8 bf16)/lane ----
// dst[r] = (1/cnt[r]) * sum src[members]; 4 rows per wave, 16 B/lane loads:
// 4x the bytes in flight of the half-wave version (latency-bound loop).
// STATS: per-lane 8-column raw moments -> LDS -> one 256-atomic flush/block.
template<int STATS>
__global__ __launch_bounds__(256) void gather_q(
    const u16* __restrict__ src, const int* __restrict__ cnt,
    const int* __restrict__ col, u16* __restrict__ dst,
    float* __restrict__ stat, float* __restrict__ zp,
    const uint2* __restrict__ ovf, const int* __restrict__ ovfCnt, int nrows)
{
    if (zp && blockIdx.x == 0) zp[threadIdx.x] = 0.0f;
    const int tid  = threadIdx.x;
    const int lane = tid & 63;
    const int ql   = lane & 15;       // lane within quarter
    const int qid  = tid >> 4;        // quarter id within block, 0..15
    const int bsel = lane & 48;       // shfl base for this quarter
    const u16* srcq = src + ql * 8;   // this lane's 8 columns
    float s1[8] = {0,0,0,0,0,0,0,0};
    float s2[8] = {0,0,0,0,0,0,0,0};

    for (int rr = blockIdx.x * 16; rr < nrows; rr += gridDim.x * 16) {
        int r = rr + qid;
        if (r < nrows) {
            int c = cnt[r];
            int cc = (c > CAP) ? CAP : c;
            int m = (ql < cc) ? col[(r << 4) + ql] : 0;
            float a[8] = {0,0,0,0,0,0,0,0};
            int j = 0;
            for (; j + 4 <= cc; j += 4) {
                int t0 = __shfl(m, bsel | j);
                int t1 = __shfl(m, bsel | (j + 1));
                int t2 = __shfl(m, bsel | (j + 2));
                int t3 = __shfl(m, bsel | (j + 3));
                uint4 va = *(const uint4*)(srcq + (size_t)t0 * 128);
                uint4 vb = *(const uint4*)(srcq + (size_t)t1 * 128);
                uint4 vc = *(const uint4*)(srcq + (size_t)t2 * 128);
                uint4 vd = *(const uint4*)(srcq + (size_t)t3 * 128);
                a[0] += bf2f((u16)(va.x & 0xFFFF)) + bf2f((u16)(vb.x & 0xFFFF))
                      + bf2f((u16)(vc.x & 0xFFFF)) + bf2f((u16)(vd.x & 0xFFFF));
                a[1] += bf2f((u16)(va.x >> 16)) + bf2f((u16)(vb.x >> 16))
                      + bf2f((u16)(vc.x >> 16)) + bf2f((u16)(vd.x >> 16));
                a[2] += bf2f((u16)(va.y & 0xFFFF)) + bf2f((u16)(vb.y & 0xFFFF))
                      + bf2f((u16)(vc.y & 0xFFFF)) + bf2f((u16)(vd.y & 0xFFFF));
                a[3] += bf2f((u16)(va.y >> 16)) + bf2f((u16)(vb.y >> 16))
                      + bf2f((u16)(vc.y >> 16)) + bf2f((u16)(vd.y >> 16));
                a[4] += bf2f((u16)(va.z & 0xFFFF)) + bf2f((u16)(vb.z & 0xFFFF))
                      + bf2f((u16)(vc.z & 0xFFFF)) + bf2f((u16)(vd.z & 0xFFFF));
                a[5] += bf2f((u16)(va.z >> 16)) + bf2f((u16)(vb.z >> 16))
                      + bf2f((u16)(vc.z >> 16)) + bf2f((u16)(vd.z >> 16));
                a[6] += bf2f((u16)(va.w & 0xFFFF)) + bf2f((u16)(vb.w & 0xFFFF))
                      + bf2f((u16)(vc.w & 0xFFFF)) + bf2f((u16)(vd.w & 0xFFFF));
                a[7] += bf2f((u16)(va.w >> 16)) + bf2f((u16)(vb.w >> 16))
                      + bf2f((u16)(vc.w >> 16)) + bf2f((u16)(vd.w >> 16));
            }
            for (; j < cc; j++) {
                int t0 = __shfl(m, bsel | j);
                uint4 va = *(const uint4*)(srcq + (size_t)t0 * 128);
                a[0] += bf2f((u16)(va.x & 0xFFFF)); a[1] += bf2f((u16)(va.x >> 16));
                a[2] += bf2f((u16)(va.y & 0xFFFF)); a[3] += bf2f((u16)(va.y >> 16));
                a[4] += bf2f((u16)(va.z & 0xFFFF)); a[5] += bf2f((u16)(va.z >> 16));
                a[6] += bf2f((u16)(va.w & 0xFFFF)); a[7] += bf2f((u16)(va.w >> 16));
            }
            if (c > CAP) {                 // rare: scan overflow list
                int nov = *ovfCnt; if (nov > OVF_MAX) nov = OVF_MAX;
                for (int i2 = 0; i2 < nov; i2++) {
                    uint2 p = ovf[i2];
                    if ((int)p.x == r) {
                        uint4 va = *(const uint4*)(srcq + (size_t)p.y * 128);
                        a[0] += bf2f((u16)(va.x & 0xFFFF)); a[1] += bf2f((u16)(va.x >> 16));
                        a[2] += bf2f((u16)(va.y & 0xFFFF)); a[3] += bf2f((u16)(va.y >> 16));
                        a[4] += bf2f((u16)(va.z & 0xFFFF)); a[5] += bf2f((u16)(va.z >> 16));
                        a[6] += bf2f((u16)(va.w & 0xFFFF)); a[7] += bf2f((u16)(va.w >> 16));
                    }
                }
            }
            float w = (c > 0) ? 1.0f / (float)c : 0.0f;
#pragma unroll
            for (int k = 0; k < 8; k++) a[k] *= w;
            uint4 o;
            o.x = (unsigned)f2bf(a[0]) | ((unsigned)f2bf(a[1]) << 16);
            o.y = (unsigned)f2bf(a[2]) | ((unsigned)f2bf(a[3]) << 16);
            o.z = (unsigned)f2bf(a[4]) | ((unsigned)f2bf(a[5]) << 16);
            o.w = (unsigned)f2bf(a[6]) | ((unsigned)f2bf(a[7]) << 16);
            *(uint4*)(dst + (size_t)r * 128 + ql * 8) = o;
            if (STATS) {
#pragma unroll
                for (int k = 0; k < 8; k++) { s1[k] += a[k]; s2[k] += a[k] * a[k]; }
            }
        }
    }
    if (STATS) {
        __shared__ float redS[16][128];
        __shared__ float redQ[16][128];
#pragma unroll
        for (int k = 0; k < 8; k++) {
            redS[qid][ql * 8 + k] = s1[k];
            redQ[qid][ql * 8 + k] = s2[k];
        }
        __syncthreads();
        int t = tid & 127;
        float accv = 0.0f;
        if (tid < 128) {
#pragma unroll
            for (int q = 0; q < 16; q++) accv += redS[q][t];
            atomAddF(&stat[t], accv);
        } else {
#pragma unroll
            for (int q = 0; q < 16; q++) accv += redQ[q][t];
            atomAddF(&stat[128 + t], accv);
        }
    }
}

// ---------------- MFMA classifier with fused BN on the A-path ---------------
__global__ __launch_bounds__(256) void classifier_mfma(
    const u16* __restrict__ Z, const float* __restrict__ Wc1,
    const float* __restrict__ bc1, const float* __restrict__ Wc2,
    const float* __restrict__ bc2, float* __restrict__ out, int M,
    const float* __restrict__ gsum, const float* __restrict__ gsq,
    const float* __restrict__ gam, const float* __restrict__ bet, float invM)
{
    __shared__ __attribute__((aligned(16))) u16 W1t[64 * 128];   // 16 KB
    __shared__ __attribute__((aligned(16))) u16 W2t[16 * 64];    // 2 KB
    __shared__ __attribute__((aligned(16))) u16 hs[128][72];     // 18.4 KB
    __shared__ __attribute__((aligned(16))) float As[128];
    __shared__ __attribute__((aligned(16))) float Cs[128];
    const int tid = threadIdx.x;
    if (tid < 128) {
        float s1 = gsum[tid] * invM;
        float var = gsq[tid] * invM - s1 * s1;
        if (var < 0.0f) var = 0.0f;
        float sc = gam[tid] * rsqrtf(var + 1e-5f);
        As[tid] = sc;
        Cs[tid] = bet[tid] - s1 * sc;
    }
    for (int i = tid; i < 64 * 128; i += 256) {   // i = k*64 + n
        int k = i >> 6, n = i & 63;
        int kb = k >> 3, kin = k & 7;
        W1t[n * 128 + (((kb + n) & 15) << 3) + kin] = f2bf(Wc1[i]);
    }
    for (int i = tid; i < 16 * 64; i += 256) {    // i = k*16 + n
        int k = i >> 4, n = i & 15;
        W2t[n * 64 + k] = (n < 10) ? f2bf(Wc2[k * 10 + n]) : (u16)0;
    }
    __syncthreads();

    const int wave = tid >> 6, lane = tid & 63;
    const int l16 = lane & 15, quad = lane >> 4;
    const int rowt = blockIdx.x * 128 + wave * 32;
    const int r0 = rowt + l16, r1 = rowt + 16 + l16;
    const bool v0 = r0 < M, v1 = r1 < M;
    const u16* a0p = Z + (size_t)(v0 ? r0 : 0) * 128 + quad * 8;
    const u16* a1p = Z + (size_t)(v1 ? r1 : 0) * 128 + quad * 8;

    float4v acc[2][4];
#pragma unroll
    for (int g = 0; g < 2; g++)
#pragma unroll
        for (int c = 0; c < 4; c++) acc[g][c] = (float4v)0.0f;

#pragma unroll
    for (int k0 = 0; k0 < 128; k0 += 32) {
        int kb4 = k0 + quad * 8;
        float4 A0 = *(const float4*)&As[kb4], A1 = *(const float4*)&As[kb4 + 4];
        float4 C0 = *(const float4*)&Cs[kb4], C1 = *(const float4*)&Cs[kb4 + 4];
        short8 af0 = bn_frag(*(const short8*)(a0p + k0), A0, A1, C0, C1);
        short8 af1 = bn_frag(*(const short8*)(a1p + k0), A0, A1, C0, C1);
        if (!v0) af0 = (short8)(short)0;
        if (!v1) af1 = (short8)(short)0;
        const int kb = (k0 >> 3) + quad;
#pragma unroll
        for (int c = 0; c < 4; c++) {
            const int n = c * 16 + l16;
            short8 bf = *(const short8*)&W1t[n * 128 + (((kb + n) & 15) << 3)];
            acc[0][c] = __builtin_amdgcn_mfma_f32_16x16x32_bf16(af0, bf, acc[0][c], 0, 0, 0);
            acc[1][c] = __builtin_amdgcn_mfma_f32_16x16x32_bf16(af1, bf, acc[1][c], 0, 0, 0);
        }
    }
#pragma unroll
    for (int g = 0; g < 2; g++)
#pragma unroll
        for (int c = 0; c < 4; c++) {
            float b = bc1[c * 16 + l16];
#pragma unroll
            for (int r = 0; r < 4; r++)
                hs[wave * 32 + g * 16 + quad * 4 + r][c * 16 + l16] =
                    f2bf(fmaxf(acc[g][c][r] + b, 0.0f));
        }
    asm volatile("s_waitcnt lgkmcnt(0)" ::: "memory");

    float4v a2[2];
    a2[0] = (float4v)0.0f; a2[1] = (float4v)0.0f;
#pragma unroll
    for (int k0 = 0; k0 < 64; k0 += 32) {
        short8 bf = *(const short8*)&W2t[l16 * 64 + k0 + quad * 8];
#pragma unroll
        for (int g = 0; g < 2; g++) {
            short8 af = *(const short8*)&hs[wave * 32 + g * 16 + l16][k0 + quad * 8];
            a2[g] = __builtin_amdgcn_mfma_f32_16x16x32_bf16(af, bf, a2[g], 0, 0, 0);
        }
    }
    if (l16 < 10) {
        float b2 = bc2[l16];
#pragma unroll
        for (int g = 0; g < 2; g++)
#pragma unroll
            for (int r = 0; r < 4; r++) {
                int row = rowt + g * 16 + quad * 4 + r;
                if (row < M) out[(size_t)row * 10 + l16] = a2[g][r] + b2;
            }
    }
}

// ---------------- launch ----------------------------------------------------
extern "C" void kernel_launch(void* const* d_in, const int* in_sizes, int n_in,
                              void* d_out, int out_size, void* d_ws, size_t ws_size,
                              hipStream_t stream)
{
    const int M   = N_NODES;
    const int NE  = N_EDGES;
    const int nnz = NNZ_C;

    const float* x   = (const float*)d_in[0];
    const int*  nidx = (const int*)d_in[1];
    const int*  eidx = nidx + nnz;
    const float* W1  = (const float*)d_in[2];
    const float* W2  = (const float*)d_in[4];
    const float* W3  = (const float*)d_in[6];
    const float* g1  = (const float*)d_in[8];
    const float* bt1 = (const float*)d_in[9];
    const float* g2  = (const float*)d_in[10];
    const float* bt2 = (const float*)d_in[11];
    const float* g3  = (const float*)d_in[12];
    const float* bt3 = (const float*)d_in[13];
    const float* Wc1 = (const float*)d_in[14];
    const float* bc1 = (const float*)d_in[15];
    const float* Wc2 = (const float*)d_in[16];
    const float* bc2 = (const float*)d_in[17];
    float* out = (float*)d_out;

    // ---- workspace carve-up ----
    const size_t SZH = (size_t)M * 128 * sizeof(u16);   // 25.6 MB
    char* ws = (char*)d_ws;
    u16* Y = (u16*)(ws);                     // GEMM output (bf16)
    u16* E = (u16*)(ws + SZH);               // edge features (bf16)
    u16* Z = (u16*)(ws + 2 * SZH);           // node agg, pre-BN (bf16)
    int* ib = (int*)(ws + 3 * SZH);
    int*   cb      = ib;                     // edge sizes / cursors [100000]
    int*   cd      = ib + 100000;            // node degrees / cursors
    int*   ovfCntB = ib + 200000;
    int*   ovfCntD = ib + 200001;
    int*   colB    = ib + 200016;            // 64-B aligned; [100000*16]
    int*   colD    = ib + 200016 + NE * CAP;
    uint2* ovfB    = (uint2*)(ib + 200016 + (NE + M) * CAP);
    uint2* ovfD    = ovfB + OVF_MAX;
    float* fb = (float*)(ovfD + OVF_MAX);
    float* gsum = fb;                        // [128]; gsq contiguous after
    u16* wbuf = (u16*)(fb + 256);
    u16* W1b = wbuf;                         // 2 chunks x 16384 (swizzled)
    u16* W2b = wbuf + 32768;                 // 1 chunk
    u16* W3b = wbuf + 49152;                 // 1 chunk

    const int ntiles = (M + 127) / 128;
    const float invM = 1.0f / (float)M;

    // ---- index preprocessing ----
    hipMemsetAsync(cb, 0, 800008, stream);   // cb + cd + both overflow counters
    fill_direct<<<(nnz + 255) / 256, 256, 0, stream>>>(
        nidx, eidx, cb, cd, colB, colD, ovfB, ovfD, ovfCntB, ovfCntD, nnz);
    convert_w<<<256, 256, 0, stream>>>(W1, W2, W3, W1b, W2b, W3b);

    const float* gin[3]  = { g1, g2, g3 };
    const float* btin[3] = { bt1, bt2, bt3 };
    const u16*   Wbf[3]  = { W1b, W2b, W3b };

    for (int L = 0; L < 3; L++) {
        if (L == 0)
            gemm_mfma<256, 1><<<ntiles, 256, 0, stream>>>(
                x, Wbf[0], Y, M, nullptr, nullptr, nullptr, nullptr, 0.0f);
        else
            gemm_mfma<128, 2><<<ntiles, 256, 0, stream>>>(
                Z, Wbf[L], Y, M, gsum, gsum + 128, gin[L - 1], btin[L - 1], invM);
        // edge aggregation; block 0 zeros gsum||gsq for the node pass
        gather_q<0><<<(NE + 15) / 16, 256, 0, stream>>>(
            Y, cb, colB, E, nullptr, gsum, ovfB, ovfCntB, NE);
        // node aggregation with fused raw-moment stats (2048 blocks = 8/CU)
        gather_q<1><<<2048, 256, 0, stream>>>(
            E, cd, colD, Z, gsum, nullptr, ovfD, ovfCntD, M);
    }

    classifier_mfma<<<ntiles, 256, 0, stream>>>(
        Z, Wc1, bc1, Wc2, bc2, out, M, gsum, gsum + 128, gin[2], btin[2], invM);
}